// Round 17
// baseline (160.858 us; speedup 1.0000x reference)
//
#include <hip/hip_runtime.h>
#include <math.h>

#define NB 2
#define NC 256
#define NS 4096
#define NG 32
#define CPG 8
#define NH 4
#define DK 64
#define NQKV 768
#define NKG 4
#define TPG 16
#define QS 0.18033688011112042f   /* 0.125 * log2(e) */

typedef __attribute__((ext_vector_type(8))) short short8;
typedef __attribute__((ext_vector_type(4))) float f32x4;
typedef __attribute__((ext_vector_type(16))) float f32x16;
typedef __attribute__((ext_vector_type(4))) unsigned uint4v;

union U8 { uint4v u; short8 s; };

__device__ __forceinline__ short f2bf(float f){
  union { float f; unsigned u; } v; v.f = f;
  unsigned r = v.u + 0x7fffu + ((v.u >> 16) & 1u);
  return (short)(r >> 16);
}
__device__ __forceinline__ float ex2(float x){
  float y; asm("v_exp_f32 %0, %1" : "=v"(y) : "v"(x)); return y;
}
__device__ __forceinline__ unsigned cvtpk(float lo, float hi){
  unsigned u; asm("v_cvt_pk_bf16_f32 %0, %1, %2" : "=v"(u) : "v"(lo), "v"(hi)); return u;
}
__device__ __forceinline__ void pl32swap(unsigned &x, unsigned &y){
  asm("v_permlane32_swap_b32 %0, %1" : "+v"(x), "+v"(y));
}

// ---- K1a: GN stats, 256 blocks (bg x quarter), atomicAdd partials into sbuf ----
__global__ __launch_bounds__(256) void k_stats(const float* __restrict__ x,
                                               float* __restrict__ sbuf){
  int blk = blockIdx.x;
  int bg = blk >> 2, qt = blk & 3;
  const float* base = x + (size_t)bg*(CPG*NS) + (size_t)qt*(CPG*NS/4);
  const f32x4* b4 = (const f32x4*)base;
  float s = 0.f, ss = 0.f;
  #pragma unroll
  for (int it = 0; it < 8; ++it){
    f32x4 v = b4[it*256 + threadIdx.x];
    s  += (v[0]+v[1])+(v[2]+v[3]);
    ss += (v[0]*v[0]+v[1]*v[1])+(v[2]*v[2]+v[3]*v[3]);
  }
  for (int o = 32; o > 0; o >>= 1){ s += __shfl_down(s,o); ss += __shfl_down(ss,o); }
  __shared__ float red[8];
  int w = threadIdx.x >> 6;
  if ((threadIdx.x & 63) == 0){ red[w] = s; red[4+w] = ss; }
  __syncthreads();
  if (threadIdx.x == 0){
    float S  = red[0]+red[1]+red[2]+red[3];
    float SS = red[4]+red[5]+red[6]+red[7];
    atomicAdd(&sbuf[bg], S);
    atomicAdd(&sbuf[64 + bg], SS);
  }
}

// ---- K1b: GN apply + transpose-write h (blocks 0..255), weight cvt (256..1023) ----
__global__ __launch_bounds__(256) void k_apply(const float* __restrict__ x,
                                               const float* __restrict__ sbuf,
                                               const float* __restrict__ gw,
                                               const float* __restrict__ gb,
                                               const float* __restrict__ pw,
                                               const float* __restrict__ ow,
                                               short* __restrict__ h,
                                               short* __restrict__ pwb,
                                               short* __restrict__ owb){
  int blk = blockIdx.x;
  int tid = threadIdx.x;
  if (blk < 256){
    int bg = blk >> 2, qt = blk & 3;
    int b = bg >> 5, g = bg & 31;
    const float* base = x + (size_t)bg*(CPG*NS);
    const float inv = 1.f/(float)(CPG*NS);
    float mu = sbuf[bg]*inv;
    float rs = rsqrtf(sbuf[64+bg]*inv - mu*mu + 1e-5f);
    float wv[8], bv[8];
    #pragma unroll
    for (int c = 0; c < 8; ++c){
      wv[c] = gw[g*8 + c] * rs;
      bv[c] = gb[g*8 + c] - mu * wv[c];
    }
    short* hb = h + (size_t)b*NS*NC + g*8;
    int s0 = qt << 10;
    #pragma unroll
    for (int it = 0; it < 4; ++it){
      int i = s0 + it*256 + tid;
      unsigned u[4];
      #pragma unroll
      for (int c2 = 0; c2 < 4; ++c2){
        float v0 = base[(size_t)(2*c2  )*NS + i]*wv[2*c2  ] + bv[2*c2  ];
        float v1 = base[(size_t)(2*c2+1)*NS + i]*wv[2*c2+1] + bv[2*c2+1];
        u[c2] = cvtpk(v0, v1);
      }
      *(uint4v*)&hb[(size_t)i*NC] = (uint4v){u[0],u[1],u[2],u[3]};
    }
  } else {
    int i = (blk - 256)*256 + tid;
    if (i < NQKV*NC) pwb[i] = f2bf(pw[i]);
    if (i < NC*NC)   owb[i] = f2bf(ow[i]);
  }
}

// ---- K4: QKV GEMM, BM=64 BK=64 -> 768 blocks; scatter epilogue; q gets QS folded ----
__global__ __launch_bounds__(256) void k_qkv(const short* __restrict__ h,
                                             const short* __restrict__ wb,
                                             const float* __restrict__ pb,
                                             short* __restrict__ qo,
                                             short* __restrict__ ko,
                                             short* __restrict__ vto){
  __shared__ short As[64][72];
  __shared__ short Bs[128][72];
  int m0 = blockIdx.x << 6;
  int n0 = blockIdx.y << 7;
  int tid = threadIdx.x;
  int lane = tid & 63, wid = tid >> 6;
  int wm = (wid >> 1) << 5, wn = (wid & 1) << 6;
  int l15 = lane & 15, lg = lane >> 4;
  const f32x4 fz = {0.f,0.f,0.f,0.f};
  f32x4 acc[2][4];
  for (int i=0;i<2;i++) for(int j=0;j<4;j++) acc[i][j] = fz;
  for (int k0 = 0; k0 < NC; k0 += 64){
    __syncthreads();
    for (int it = 0; it < 2; ++it){
      int c = it*256 + tid;
      int r = c >> 3, ch = (c & 7) << 3;
      *(short8*)&As[r][ch] = *(const short8*)&h[((size_t)(m0 + r))*NC + k0 + ch];
    }
    for (int it = 0; it < 4; ++it){
      int c = it*256 + tid;
      int r = c >> 3, ch = (c & 7) << 3;
      *(short8*)&Bs[r][ch] = *(const short8*)&wb[((size_t)(n0 + r))*NC + k0 + ch];
    }
    __syncthreads();
    #pragma unroll
    for (int kk = 0; kk < 2; ++kk){
      short8 a[2], b[4];
      for (int mf=0; mf<2; ++mf) a[mf] = *(const short8*)&As[wm + mf*16 + l15][kk*32 + lg*8];
      for (int nf=0; nf<4; ++nf) b[nf] = *(const short8*)&Bs[wn + nf*16 + l15][kk*32 + lg*8];
      for (int mf=0; mf<2; ++mf)
        for (int nf=0; nf<4; ++nf)
          acc[mf][nf] = __builtin_amdgcn_mfma_f32_16x16x32_bf16(a[mf], b[nf], acc[mf][nf], 0,0,0);
    }
  }
  for (int mf=0; mf<2; ++mf)
    for (int nf=0; nf<4; ++nf)
      for (int r=0; r<4; ++r){
        int m = m0 + wm + mf*16 + lg*4 + r;
        int o = n0 + wn + nf*16 + l15;
        float val = acc[mf][nf][r] + pb[o];
        int b_ = m >> 12, s = m & 4095;
        int hh = o / 192, rem = o - hh*192;
        int t = rem >> 6, d = rem & 63;
        size_t bh = (size_t)(b_*NH + hh);
        if (t == 0)      qo [(bh*NS + s)*DK + d] = f2bf(val * QS);
        else if (t == 1) ko [(bh*NS + s)*DK + d] = f2bf(val);
        else             vto[(bh*DK + d)*NS + s] = f2bf(val);
      }
}

// ---- K5: flash attention, NO-LDS-staging variant: K/V read directly from L2
//          (per-bh K/V = 1MB, L2-resident via XCD swizzle). Zero barriers in the
//          main loop -> waves free-run; LDS only holds the 4-way merge overlay. ----
struct SMC {
  float gOB[3][4][64][33];
  float ml[3][4][2][32];
  float fOB[4][64][33];
};                                    // 138,240 B

__global__ __launch_bounds__(1024, 4) void k_attn(const short* __restrict__ q,
                                                  const short* __restrict__ k,
                                                  const short* __restrict__ vt,
                                                  short* __restrict__ ao){
  extern __shared__ char smem[];
  SMC* sc = (SMC*)smem;

  int blk = blockIdx.x;
  int bh = blk & 7;                  // XCD-locality: one bh's 1MB K/V per XCD L2
  int q0 = (blk >> 3) << 7;
  const short* Qb = q  + (size_t)bh*NS*DK;
  const short* Kb = k  + (size_t)bh*NS*DK;
  const short* Vb = vt + (size_t)bh*DK*NS;
  int tid = threadIdx.x, lane = tid & 63, wid = tid >> 6;
  int l31 = lane & 31, hi = lane >> 5;
  int g = wid >> 2, wq = wid & 3;
  int kvbase = g << 10;

  short8 bq[4];
  {
    const short* qrow = Qb + (size_t)(q0 + wq*32 + l31)*DK + hi*8;
    #pragma unroll
    for (int s2 = 0; s2 < 4; ++s2) bq[s2] = *(const short8*)(qrow + s2*16);
  }

  f32x16 ot0, ot1;
  #pragma unroll
  for (int i = 0; i < 16; ++i){ ot0[i] = 0.f; ot1[i] = 0.f; }
  float mrun = -1e30f, lrun = 0.f;

  // per-wave direct-L2 fragment pointers (advance per tile)
  const short* Kp0 = Kb + (size_t)(kvbase + l31)*DK + hi*8;
  const short* Kp1 = Kp0 + 32*DK;
  const short* Vp0 = Vb + (size_t)l31*NS + kvbase + hi*8;
  const short* Vp1 = Vp0 + (size_t)32*NS;

  for (int t = 0; t < TPG; ++t){
    // K fragments: 8 independent 16B L2 loads, all in flight before MFMAs
    short8 ka0[4], ka1[4];
    #pragma unroll
    for (int s2 = 0; s2 < 4; ++s2){
      ka0[s2] = *(const short8*)(Kp0 + s2*16);
      ka1[s2] = *(const short8*)(Kp1 + s2*16);
    }
    f32x16 st0, st1;
    #pragma unroll
    for (int i = 0; i < 16; ++i){ st0[i] = 0.f; st1[i] = 0.f; }
    #pragma unroll
    for (int s2 = 0; s2 < 4; ++s2){
      st0 = __builtin_amdgcn_mfma_f32_32x32x16_bf16(ka0[s2], bq[s2], st0, 0,0,0);
      st1 = __builtin_amdgcn_mfma_f32_32x32x16_bf16(ka1[s2], bq[s2], st1, 0,0,0);
    }
    float mx = -1e30f;
    #pragma unroll
    for (int i = 0; i < 16; ++i) mx = fmaxf(mx, fmaxf(st0[i], st1[i]));
    mx = fmaxf(mx, __shfl_xor(mx, 32));
    if (!__all(mx - mrun <= 8.f)){   // defer-rescale: P bounded by 2^8
      float mnew = fmaxf(mrun, mx);
      float corr = ex2(mrun - mnew);
      lrun *= corr;
      #pragma unroll
      for (int i = 0; i < 16; ++i){ ot0[i] *= corr; ot1[i] *= corr; }
      mrun = mnew;
    }
    float p0[16], p1[16]; float ps = 0.f;
    #pragma unroll
    for (int i = 0; i < 16; ++i){
      p0[i] = ex2(st0[i] - mrun); p1[i] = ex2(st1[i] - mrun);
      ps += p0[i] + p1[i];
    }
    ps += __shfl_xor(ps, 32);
    lrun += ps;
    unsigned pk0[8], pk1[8];
    #pragma unroll
    for (int a = 0; a < 4; ++a){
      pk0[a]     = cvtpk(p0[4*a+0], p0[4*a+1]);
      pk1[a]     = cvtpk(p0[4*a+2], p0[4*a+3]);
      pk0[4 + a] = cvtpk(p1[4*a+0], p1[4*a+1]);
      pk1[4 + a] = cvtpk(p1[4*a+2], p1[4*a+3]);
    }
    #pragma unroll
    for (int i2 = 0; i2 < 4; ++i2){
      short8 av0 = *(const short8*)(Vp0 + i2*16);   // direct L2
      short8 av1 = *(const short8*)(Vp1 + i2*16);
      unsigned w0 = pk0[2*i2], w2 = pk0[2*i2+1]; pl32swap(w0, w2);
      unsigned w1 = pk1[2*i2], w3 = pk1[2*i2+1]; pl32swap(w1, w3);
      U8 cv; cv.u = (uint4v){w0, w1, w2, w3};
      ot0 = __builtin_amdgcn_mfma_f32_32x32x16_bf16(av0, cv.s, ot0, 0,0,0);
      ot1 = __builtin_amdgcn_mfma_f32_32x32x16_bf16(av1, cv.s, ot1, 0,0,0);
    }
    Kp0 += 64*DK; Kp1 += 64*DK;
    Vp0 += 64;    Vp1 += 64;
  }

  // ---- 4-way merge through LDS (only synchronization in the kernel) ----
  __syncthreads();
  if (g > 0){
    #pragma unroll
    for (int r2 = 0; r2 < 16; ++r2){
      int dl = (r2 & 3) + 8*(r2 >> 2) + 4*hi;
      sc->gOB[g-1][wq][dl][l31]      = ot0[r2];
      sc->gOB[g-1][wq][32 + dl][l31] = ot1[r2];
    }
    if (hi == 0){ sc->ml[g-1][wq][0][l31] = mrun; sc->ml[g-1][wq][1][l31] = lrun; }
  }
  __syncthreads();
  if (g == 0){
    float m1 = sc->ml[0][wq][0][l31], l1 = sc->ml[0][wq][1][l31];
    float m2 = sc->ml[1][wq][0][l31], l2 = sc->ml[1][wq][1][l31];
    float m3 = sc->ml[2][wq][0][l31], l3 = sc->ml[2][wq][1][l31];
    float M  = fmaxf(fmaxf(mrun, m1), fmaxf(m2, m3));
    float w0 = ex2(mrun - M), w1 = ex2(m1 - M), w2 = ex2(m2 - M), w3 = ex2(m3 - M);
    float inv = 1.f/(lrun*w0 + l1*w1 + l2*w2 + l3*w3);
    w0 *= inv; w1 *= inv; w2 *= inv; w3 *= inv;
    #pragma unroll
    for (int r2 = 0; r2 < 16; ++r2){
      int dl = (r2 & 3) + 8*(r2 >> 2) + 4*hi;
      sc->fOB[wq][dl][l31] = ot0[r2]*w0 + sc->gOB[0][wq][dl][l31]*w1
                           + sc->gOB[1][wq][dl][l31]*w2 + sc->gOB[2][wq][dl][l31]*w3;
      sc->fOB[wq][32+dl][l31] = ot1[r2]*w0 + sc->gOB[0][wq][32+dl][l31]*w1
                              + sc->gOB[1][wq][32+dl][l31]*w2 + sc->gOB[2][wq][32+dl][l31]*w3;
    }
  }
  __syncthreads();
  {
    int ql = tid >> 3, dc = (tid & 7) << 3;
    int b_ = bh >> 2, hh = bh & 3;
    float v2[8];
    #pragma unroll
    for (int i = 0; i < 8; ++i) v2[i] = sc->fOB[ql >> 5][dc + i][ql & 31];
    uint4v wa = { cvtpk(v2[0],v2[1]), cvtpk(v2[2],v2[3]),
                  cvtpk(v2[4],v2[5]), cvtpk(v2[6],v2[7]) };
    size_t base = ((size_t)b_*NS + q0 + ql)*NC + hh*DK + dc;
    *(uint4v*)&ao[base] = wa;
  }
}

// ---- K6: out GEMM + bias + residual, BM=64 BN=64 -> 512 blocks ----
__global__ __launch_bounds__(256) void k_out(const short* __restrict__ aoin,
                                             const short* __restrict__ wb,
                                             const float* __restrict__ ob,
                                             const float* __restrict__ x,
                                             float* __restrict__ out){
  __shared__ short As[64][40];
  __shared__ short Bs[64][40];
  int m0 = blockIdx.x << 6;
  int n0 = blockIdx.y << 6;
  int tid = threadIdx.x;
  int lane = tid & 63, wid = tid >> 6;
  int wm = (wid >> 1) << 5, wn = (wid & 1) << 5;
  int l15 = lane & 15, lg = lane >> 4;
  const f32x4 fz = {0.f,0.f,0.f,0.f};
  f32x4 acc[2][2];
  for (int i=0;i<2;i++) for(int j=0;j<2;j++) acc[i][j] = fz;
  for (int k0 = 0; k0 < NC; k0 += 32){
    __syncthreads();
    {
      int c = tid;
      int r = c >> 2, kk8 = (c & 3) << 3;
      *(short8*)&As[r][kk8] = *(const short8*)&aoin[((size_t)(m0 + r))*NC + k0 + kk8];
      *(short8*)&Bs[r][kk8] = *(const short8*)&wb  [((size_t)(n0 + r))*NC + k0 + kk8];
    }
    __syncthreads();
    short8 a[2], b[2];
    for (int mf=0; mf<2; ++mf) a[mf] = *(const short8*)&As[wm + mf*16 + l15][lg*8];
    for (int nf=0; nf<2; ++nf) b[nf] = *(const short8*)&Bs[wn + nf*16 + l15][lg*8];
    for (int mf=0; mf<2; ++mf)
      for (int nf=0; nf<2; ++nf)
        acc[mf][nf] = __builtin_amdgcn_mfma_f32_16x16x32_bf16(a[mf], b[nf], acc[mf][nf], 0,0,0);
  }
  for (int mf=0; mf<2; ++mf)
    for (int nf=0; nf<2; ++nf)
      for (int r=0; r<4; ++r){
        int m = m0 + wm + mf*16 + lg*4 + r;
        int o = n0 + wn + nf*16 + l15;
        int b_ = m >> 12, s = m & 4095;
        size_t idx = ((size_t)b_*NC + o)*NS + s;
        out[idx] = acc[mf][nf][r] + ob[o] + x[idx];
      }
}

extern "C" void kernel_launch(void* const* d_in, const int* in_sizes, int n_in,
                              void* d_out, int out_size, void* d_ws, size_t ws_size,
                              hipStream_t stream){
  const float* x   = (const float*)d_in[0];
  const float* gnw = (const float*)d_in[1];
  const float* gnb = (const float*)d_in[2];
  const float* pw  = (const float*)d_in[3];
  const float* pb  = (const float*)d_in[4];
  const float* ow  = (const float*)d_in[5];
  const float* ob  = (const float*)d_in[6];
  float* out = (float*)d_out;

  char* ws = (char*)d_ws;
  float* sbuf = (float*)ws;                          // [128] f32: S[64], SS[64]
  short* wqkv = (short*)(ws + 512);
  short* wout = wqkv + NQKV*NC;
  short* h    = wout + NC*NC;
  short* qb   = h   + (size_t)NB*NS*NC;
  short* kb   = qb  + (size_t)NB*NH*NS*DK;
  short* vtb  = kb  + (size_t)NB*NH*NS*DK;
  short* ao   = vtb + (size_t)NB*NH*NS*DK;

  hipMemsetAsync(sbuf, 0, 512, stream);
  k_stats<<<256, 256, 0, stream>>>(x, sbuf);
  k_apply<<<1024, 256, 0, stream>>>(x, sbuf, gnw, gnb, pw, ow, h, wqkv, wout);
  k_qkv<<<dim3(128, 6), 256, 0, stream>>>(h, wqkv, pb, qb, kb, vtb);
  k_attn<<<256, 1024, sizeof(SMC), stream>>>(qb, kb, vtb, ao);
  k_out<<<dim3(128, 4), 256, 0, stream>>>(ao, wout, ob, x, out);
}

// Round 18
// 90.419 us; speedup vs baseline: 1.7790x; 1.7790x over previous
//
#include <hip/hip_runtime.h>
#include <math.h>

#define NB 2
#define NC 256
#define NS 4096
#define NG 32
#define CPG 8
#define NH 4
#define DK 64
#define NQKV 768
#define NKG 4
#define TPG 16
#define QS 0.18033688011112042f   /* 0.125 * log2(e) */

typedef __attribute__((ext_vector_type(8))) short short8;
typedef __attribute__((ext_vector_type(4))) float f32x4;
typedef __attribute__((ext_vector_type(16))) float f32x16;
typedef __attribute__((ext_vector_type(4))) unsigned uint4v;

union U8 { uint4v u; short8 s; };

__device__ __forceinline__ short f2bf(float f){
  union { float f; unsigned u; } v; v.f = f;
  unsigned r = v.u + 0x7fffu + ((v.u >> 16) & 1u);
  return (short)(r >> 16);
}
__device__ __forceinline__ float ex2(float x){
  float y; asm("v_exp_f32 %0, %1" : "=v"(y) : "v"(x)); return y;
}
__device__ __forceinline__ unsigned cvtpk(float lo, float hi){
  unsigned u; asm("v_cvt_pk_bf16_f32 %0, %1, %2" : "=v"(u) : "v"(lo), "v"(hi)); return u;
}
__device__ __forceinline__ void pl32swap(unsigned &x, unsigned &y){
  asm("v_permlane32_swap_b32 %0, %1" : "+v"(x), "+v"(y));
}

// ---- K1a: GN stats (blocks 0..255) + weight cvt (blocks 256..1023, concurrent) ----
__global__ __launch_bounds__(256) void k_stats(const float* __restrict__ x,
                                               const float* __restrict__ pw,
                                               const float* __restrict__ ow,
                                               float* __restrict__ sbuf,
                                               short* __restrict__ pwb,
                                               short* __restrict__ owb){
  int blk = blockIdx.x;
  if (blk < 256){
    int bg = blk >> 2, qt = blk & 3;
    const float* base = x + (size_t)bg*(CPG*NS) + (size_t)qt*(CPG*NS/4);
    const f32x4* b4 = (const f32x4*)base;
    float s = 0.f, ss = 0.f;
    #pragma unroll
    for (int it = 0; it < 8; ++it){
      f32x4 v = b4[it*256 + threadIdx.x];
      s  += (v[0]+v[1])+(v[2]+v[3]);
      ss += (v[0]*v[0]+v[1]*v[1])+(v[2]*v[2]+v[3]*v[3]);
    }
    for (int o = 32; o > 0; o >>= 1){ s += __shfl_down(s,o); ss += __shfl_down(ss,o); }
    __shared__ float red[8];
    int w = threadIdx.x >> 6;
    if ((threadIdx.x & 63) == 0){ red[w] = s; red[4+w] = ss; }
    __syncthreads();
    if (threadIdx.x == 0){
      float S  = red[0]+red[1]+red[2]+red[3];
      float SS = red[4]+red[5]+red[6]+red[7];
      atomicAdd(&sbuf[bg], S);
      atomicAdd(&sbuf[64 + bg], SS);
    }
  } else {
    int i = (blk - 256)*256 + threadIdx.x;
    if (i < NQKV*NC) pwb[i] = f2bf(pw[i]);
    if (i < NC*NC)   owb[i] = f2bf(ow[i]);
  }
}

// ---- K1b: GN apply + transpose-write h (256 blocks) ----
__global__ __launch_bounds__(256) void k_apply(const float* __restrict__ x,
                                               const float* __restrict__ sbuf,
                                               const float* __restrict__ gw,
                                               const float* __restrict__ gb,
                                               short* __restrict__ h){
  int blk = blockIdx.x;
  int tid = threadIdx.x;
  int bg = blk >> 2, qt = blk & 3;
  int b = bg >> 5, g = bg & 31;
  const float* base = x + (size_t)bg*(CPG*NS);
  const float inv = 1.f/(float)(CPG*NS);
  float mu = sbuf[bg]*inv;
  float rs = rsqrtf(sbuf[64+bg]*inv - mu*mu + 1e-5f);
  float wv[8], bv[8];
  #pragma unroll
  for (int c = 0; c < 8; ++c){
    wv[c] = gw[g*8 + c] * rs;
    bv[c] = gb[g*8 + c] - mu * wv[c];
  }
  short* hb = h + (size_t)b*NS*NC + g*8;
  int s0 = qt << 10;
  #pragma unroll
  for (int it = 0; it < 4; ++it){
    int i = s0 + it*256 + tid;
    unsigned u[4];
    #pragma unroll
    for (int c2 = 0; c2 < 4; ++c2){
      float v0 = base[(size_t)(2*c2  )*NS + i]*wv[2*c2  ] + bv[2*c2  ];
      float v1 = base[(size_t)(2*c2+1)*NS + i]*wv[2*c2+1] + bv[2*c2+1];
      u[c2] = cvtpk(v0, v1);
    }
    *(uint4v*)&hb[(size_t)i*NC] = (uint4v){u[0],u[1],u[2],u[3]};
  }
}

// ---- K4: QKV GEMM, BM=64 BK=64 -> 768 blocks; scatter epilogue; q gets QS folded ----
__global__ __launch_bounds__(256) void k_qkv(const short* __restrict__ h,
                                             const short* __restrict__ wb,
                                             const float* __restrict__ pb,
                                             short* __restrict__ qo,
                                             short* __restrict__ ko,
                                             short* __restrict__ vto){
  __shared__ short As[64][72];
  __shared__ short Bs[128][72];
  int m0 = blockIdx.x << 6;
  int n0 = blockIdx.y << 7;
  int tid = threadIdx.x;
  int lane = tid & 63, wid = tid >> 6;
  int wm = (wid >> 1) << 5, wn = (wid & 1) << 6;
  int l15 = lane & 15, lg = lane >> 4;
  const f32x4 fz = {0.f,0.f,0.f,0.f};
  f32x4 acc[2][4];
  for (int i=0;i<2;i++) for(int j=0;j<4;j++) acc[i][j] = fz;
  for (int k0 = 0; k0 < NC; k0 += 64){
    __syncthreads();
    for (int it = 0; it < 2; ++it){
      int c = it*256 + tid;
      int r = c >> 3, ch = (c & 7) << 3;
      *(short8*)&As[r][ch] = *(const short8*)&h[((size_t)(m0 + r))*NC + k0 + ch];
    }
    for (int it = 0; it < 4; ++it){
      int c = it*256 + tid;
      int r = c >> 3, ch = (c & 7) << 3;
      *(short8*)&Bs[r][ch] = *(const short8*)&wb[((size_t)(n0 + r))*NC + k0 + ch];
    }
    __syncthreads();
    #pragma unroll
    for (int kk = 0; kk < 2; ++kk){
      short8 a[2], b[4];
      for (int mf=0; mf<2; ++mf) a[mf] = *(const short8*)&As[wm + mf*16 + l15][kk*32 + lg*8];
      for (int nf=0; nf<4; ++nf) b[nf] = *(const short8*)&Bs[wn + nf*16 + l15][kk*32 + lg*8];
      for (int mf=0; mf<2; ++mf)
        for (int nf=0; nf<4; ++nf)
          acc[mf][nf] = __builtin_amdgcn_mfma_f32_16x16x32_bf16(a[mf], b[nf], acc[mf][nf], 0,0,0);
    }
  }
  for (int mf=0; mf<2; ++mf)
    for (int nf=0; nf<4; ++nf)
      for (int r=0; r<4; ++r){
        int m = m0 + wm + mf*16 + lg*4 + r;
        int o = n0 + wn + nf*16 + l15;
        float val = acc[mf][nf][r] + pb[o];
        int b_ = m >> 12, s = m & 4095;
        int hh = o / 192, rem = o - hh*192;
        int t = rem >> 6, d = rem & 63;
        size_t bh = (size_t)(b_*NH + hh);
        if (t == 0)      qo [(bh*NS + s)*DK + d] = f2bf(val * QS);
        else if (t == 1) ko [(bh*NS + s)*DK + d] = f2bf(val);
        else             vto[(bh*DK + d)*NS + s] = f2bf(val);
      }
}

// ---- K5: flash attention (R16-proven body): 256 blocks x 16 waves, dbuf LDS
//          (1 barrier/tile), defer-rescale, XCD swizzle, serial softmax chains ----
struct SMK { short kv[NKG][2][2][64][72]; };   // 147456 B
struct SMC {
  float gOB[3][4][64][33];
  float ml[3][4][2][32];
  float fOB[4][64][33];
};

__global__ __launch_bounds__(1024, 4) void k_attn(const short* __restrict__ q,
                                                  const short* __restrict__ k,
                                                  const short* __restrict__ vt,
                                                  short* __restrict__ ao){
  extern __shared__ char smem[];
  SMK* sk = (SMK*)smem;
  SMC* sc = (SMC*)smem;

  int blk = blockIdx.x;
  int bh = blk & 7;                  // XCD-locality: one bh's 1MB K/V per XCD L2
  int q0 = (blk >> 3) << 7;
  const short* Qb = q  + (size_t)bh*NS*DK;
  const short* Kb = k  + (size_t)bh*NS*DK;
  const short* Vb = vt + (size_t)bh*DK*NS;
  int tid = threadIdx.x, lane = tid & 63, wid = tid >> 6;
  int l31 = lane & 31, hi = lane >> 5;
  int g = wid >> 2, wq = wid & 3;
  int gtid = tid & 255;
  int kvbase = g << 10;

  short8 bq[4];
  {
    const short* qrow = Qb + (size_t)(q0 + wq*32 + l31)*DK + hi*8;
    #pragma unroll
    for (int s2 = 0; s2 < 4; ++s2) bq[s2] = *(const short8*)(qrow + s2*16);
  }

  f32x16 ot0, ot1;
  #pragma unroll
  for (int i = 0; i < 16; ++i){ ot0[i] = 0.f; ot1[i] = 0.f; }
  float mrun = -1e30f, lrun = 0.f;

  short8 kpre[2], vpre[2];
  #pragma unroll
  for (int it = 0; it < 2; ++it){
    int c = it*256 + gtid, r = c >> 3, col = (c & 7) << 3;
    kpre[it] = *(const short8*)&Kb[(size_t)(kvbase + r)*DK + col];
    vpre[it] = *(const short8*)&Vb[(size_t)r*NS + kvbase + col];
  }
  #pragma unroll
  for (int it = 0; it < 2; ++it){
    int c = it*256 + gtid, r = c >> 3, col = (c & 7) << 3;
    *(short8*)&sk->kv[g][0][0][r][col] = kpre[it];
    *(short8*)&sk->kv[g][0][1][r][col] = vpre[it];
  }
  #pragma unroll
  for (int it = 0; it < 2; ++it){
    int c = it*256 + gtid, r = c >> 3, col = (c & 7) << 3;
    kpre[it] = *(const short8*)&Kb[(size_t)(kvbase + 64 + r)*DK + col];
    vpre[it] = *(const short8*)&Vb[(size_t)r*NS + kvbase + 64 + col];
  }

  for (int t = 0; t < TPG; ++t){
    __syncthreads();
    const short (*Kl)[72] = sk->kv[g][t & 1][0];
    const short (*Vl)[72] = sk->kv[g][t & 1][1];
    f32x16 st0, st1;
    #pragma unroll
    for (int i = 0; i < 16; ++i){ st0[i] = 0.f; st1[i] = 0.f; }
    const short* Kr0 = &Kl[l31][hi*8];
    const short* Kr1 = &Kl[32 + l31][hi*8];
    #pragma unroll
    for (int s2 = 0; s2 < 4; ++s2){
      short8 ka0 = *(const short8*)(Kr0 + s2*16);
      short8 ka1 = *(const short8*)(Kr1 + s2*16);
      st0 = __builtin_amdgcn_mfma_f32_32x32x16_bf16(ka0, bq[s2], st0, 0,0,0);
      st1 = __builtin_amdgcn_mfma_f32_32x32x16_bf16(ka1, bq[s2], st1, 0,0,0);
    }
    if (t + 1 < TPG){
      int nb = (t + 1) & 1;
      #pragma unroll
      for (int it = 0; it < 2; ++it){
        int c = it*256 + gtid, r = c >> 3, col = (c & 7) << 3;
        *(short8*)&sk->kv[g][nb][0][r][col] = kpre[it];
        *(short8*)&sk->kv[g][nb][1][r][col] = vpre[it];
      }
    }
    if (t + 2 < TPG){
      int kv0 = kvbase + (t + 2)*64;
      #pragma unroll
      for (int it = 0; it < 2; ++it){
        int c = it*256 + gtid, r = c >> 3, col = (c & 7) << 3;
        kpre[it] = *(const short8*)&Kb[(size_t)(kv0 + r)*DK + col];
        vpre[it] = *(const short8*)&Vb[(size_t)r*NS + kv0 + col];
      }
    }
    float mx = -1e30f;
    #pragma unroll
    for (int i = 0; i < 16; ++i) mx = fmaxf(mx, fmaxf(st0[i], st1[i]));
    mx = fmaxf(mx, __shfl_xor(mx, 32));
    if (!__all(mx - mrun <= 8.f)){   // defer-rescale: P bounded by 2^8
      float mnew = fmaxf(mrun, mx);
      float corr = ex2(mrun - mnew);
      lrun *= corr;
      #pragma unroll
      for (int i = 0; i < 16; ++i){ ot0[i] *= corr; ot1[i] *= corr; }
      mrun = mnew;
    }
    float p0[16], p1[16]; float ps = 0.f;
    #pragma unroll
    for (int i = 0; i < 16; ++i){
      p0[i] = ex2(st0[i] - mrun); p1[i] = ex2(st1[i] - mrun);
      ps += p0[i] + p1[i];
    }
    ps += __shfl_xor(ps, 32);
    lrun += ps;
    unsigned pk0[8], pk1[8];
    #pragma unroll
    for (int a = 0; a < 4; ++a){
      pk0[a]     = cvtpk(p0[4*a+0], p0[4*a+1]);
      pk1[a]     = cvtpk(p0[4*a+2], p0[4*a+3]);
      pk0[4 + a] = cvtpk(p1[4*a+0], p1[4*a+1]);
      pk1[4 + a] = cvtpk(p1[4*a+2], p1[4*a+3]);
    }
    const short* Vr0 = &Vl[l31][hi*8];
    const short* Vr1 = &Vl[32 + l31][hi*8];
    #pragma unroll
    for (int i2 = 0; i2 < 4; ++i2){
      unsigned w0 = pk0[2*i2], w2 = pk0[2*i2+1]; pl32swap(w0, w2);
      unsigned w1 = pk1[2*i2], w3 = pk1[2*i2+1]; pl32swap(w1, w3);
      U8 cv; cv.u = (uint4v){w0, w1, w2, w3};
      short8 av0 = *(const short8*)(Vr0 + i2*16);
      short8 av1 = *(const short8*)(Vr1 + i2*16);
      ot0 = __builtin_amdgcn_mfma_f32_32x32x16_bf16(av0, cv.s, ot0, 0,0,0);
      ot1 = __builtin_amdgcn_mfma_f32_32x32x16_bf16(av1, cv.s, ot1, 0,0,0);
    }
  }

  __syncthreads();
  if (g > 0){
    #pragma unroll
    for (int r2 = 0; r2 < 16; ++r2){
      int dl = (r2 & 3) + 8*(r2 >> 2) + 4*hi;
      sc->gOB[g-1][wq][dl][l31]      = ot0[r2];
      sc->gOB[g-1][wq][32 + dl][l31] = ot1[r2];
    }
    if (hi == 0){ sc->ml[g-1][wq][0][l31] = mrun; sc->ml[g-1][wq][1][l31] = lrun; }
  }
  __syncthreads();
  if (g == 0){
    float m1 = sc->ml[0][wq][0][l31], l1 = sc->ml[0][wq][1][l31];
    float m2 = sc->ml[1][wq][0][l31], l2 = sc->ml[1][wq][1][l31];
    float m3 = sc->ml[2][wq][0][l31], l3 = sc->ml[2][wq][1][l31];
    float M  = fmaxf(fmaxf(mrun, m1), fmaxf(m2, m3));
    float w0 = ex2(mrun - M), w1 = ex2(m1 - M), w2 = ex2(m2 - M), w3 = ex2(m3 - M);
    float inv = 1.f/(lrun*w0 + l1*w1 + l2*w2 + l3*w3);
    w0 *= inv; w1 *= inv; w2 *= inv; w3 *= inv;
    #pragma unroll
    for (int r2 = 0; r2 < 16; ++r2){
      int dl = (r2 & 3) + 8*(r2 >> 2) + 4*hi;
      sc->fOB[wq][dl][l31] = ot0[r2]*w0 + sc->gOB[0][wq][dl][l31]*w1
                           + sc->gOB[1][wq][dl][l31]*w2 + sc->gOB[2][wq][dl][l31]*w3;
      sc->fOB[wq][32+dl][l31] = ot1[r2]*w0 + sc->gOB[0][wq][32+dl][l31]*w1
                              + sc->gOB[1][wq][32+dl][l31]*w2 + sc->gOB[2][wq][32+dl][l31]*w3;
    }
  }
  __syncthreads();
  {
    int ql = tid >> 3, dc = (tid & 7) << 3;
    int b_ = bh >> 2, hh = bh & 3;
    float v2[8];
    #pragma unroll
    for (int i = 0; i < 8; ++i) v2[i] = sc->fOB[ql >> 5][dc + i][ql & 31];
    uint4v wa = { cvtpk(v2[0],v2[1]), cvtpk(v2[2],v2[3]),
                  cvtpk(v2[4],v2[5]), cvtpk(v2[6],v2[7]) };
    size_t base = ((size_t)b_*NS + q0 + ql)*NC + hh*DK + dc;
    *(uint4v*)&ao[base] = wa;
  }
}

// ---- K6: out GEMM + bias + residual, BM=64 BN=64 -> 512 blocks ----
__global__ __launch_bounds__(256) void k_out(const short* __restrict__ aoin,
                                             const short* __restrict__ wb,
                                             const float* __restrict__ ob,
                                             const float* __restrict__ x,
                                             float* __restrict__ out){
  __shared__ short As[64][40];
  __shared__ short Bs[64][40];
  int m0 = blockIdx.x << 6;
  int n0 = blockIdx.y << 6;
  int tid = threadIdx.x;
  int lane = tid & 63, wid = tid >> 6;
  int wm = (wid >> 1) << 5, wn = (wid & 1) << 5;
  int l15 = lane & 15, lg = lane >> 4;
  const f32x4 fz = {0.f,0.f,0.f,0.f};
  f32x4 acc[2][2];
  for (int i=0;i<2;i++) for(int j=0;j<2;j++) acc[i][j] = fz;
  for (int k0 = 0; k0 < NC; k0 += 32){
    __syncthreads();
    {
      int c = tid;
      int r = c >> 2, kk8 = (c & 3) << 3;
      *(short8*)&As[r][kk8] = *(const short8*)&aoin[((size_t)(m0 + r))*NC + k0 + kk8];
      *(short8*)&Bs[r][kk8] = *(const short8*)&wb  [((size_t)(n0 + r))*NC + k0 + kk8];
    }
    __syncthreads();
    short8 a[2], b[2];
    for (int mf=0; mf<2; ++mf) a[mf] = *(const short8*)&As[wm + mf*16 + l15][lg*8];
    for (int nf=0; nf<2; ++nf) b[nf] = *(const short8*)&Bs[wn + nf*16 + l15][lg*8];
    for (int mf=0; mf<2; ++mf)
      for (int nf=0; nf<2; ++nf)
        acc[mf][nf] = __builtin_amdgcn_mfma_f32_16x16x32_bf16(a[mf], b[nf], acc[mf][nf], 0,0,0);
  }
  for (int mf=0; mf<2; ++mf)
    for (int nf=0; nf<2; ++nf)
      for (int r=0; r<4; ++r){
        int m = m0 + wm + mf*16 + lg*4 + r;
        int o = n0 + wn + nf*16 + l15;
        int b_ = m >> 12, s = m & 4095;
        size_t idx = ((size_t)b_*NC + o)*NS + s;
        out[idx] = acc[mf][nf][r] + ob[o] + x[idx];
      }
}

extern "C" void kernel_launch(void* const* d_in, const int* in_sizes, int n_in,
                              void* d_out, int out_size, void* d_ws, size_t ws_size,
                              hipStream_t stream){
  const float* x   = (const float*)d_in[0];
  const float* gnw = (const float*)d_in[1];
  const float* gnb = (const float*)d_in[2];
  const float* pw  = (const float*)d_in[3];
  const float* pb  = (const float*)d_in[4];
  const float* ow  = (const float*)d_in[5];
  const float* ob  = (const float*)d_in[6];
  float* out = (float*)d_out;

  char* ws = (char*)d_ws;
  float* sbuf = (float*)ws;                          // [128] f32: S[64], SS[64]
  short* wqkv = (short*)(ws + 512);
  short* wout = wqkv + NQKV*NC;
  short* h    = wout + NC*NC;
  short* qb   = h   + (size_t)NB*NS*NC;
  short* kb   = qb  + (size_t)NB*NH*NS*DK;
  short* vtb  = kb  + (size_t)NB*NH*NS*DK;
  short* ao   = vtb + (size_t)NB*NH*NS*DK;

  hipMemsetAsync(sbuf, 0, 512, stream);
  k_stats<<<1024, 256, 0, stream>>>(x, pw, ow, sbuf, wqkv, wout);
  k_apply<<<256, 256, 0, stream>>>(x, sbuf, gnw, gnb, h);
  k_qkv<<<dim3(128, 6), 256, 0, stream>>>(h, wqkv, pb, qb, kb, vtb);
  k_attn<<<256, 1024, sizeof(SMK), stream>>>(qb, kb, vtb, ao);
  k_out<<<dim3(128, 4), 256, 0, stream>>>(ao, wout, ob, x, out);
}

// Round 19
// 86.365 us; speedup vs baseline: 1.8625x; 1.0469x over previous
//
#include <hip/hip_runtime.h>
#include <math.h>

#define NB 2
#define NC 256
#define NS 4096
#define NG 32
#define CPG 8
#define NH 4
#define DK 64
#define NQKV 768
#define NKG 4
#define TPG 16
#define QS 0.18033688011112042f   /* 0.125 * log2(e) */

typedef __attribute__((ext_vector_type(8))) short short8;
typedef __attribute__((ext_vector_type(2))) float f32x2;
typedef __attribute__((ext_vector_type(4))) float f32x4;
typedef __attribute__((ext_vector_type(16))) float f32x16;
typedef __attribute__((ext_vector_type(4))) unsigned uint4v;

union U8 { uint4v u; short8 s; };

__device__ __forceinline__ short f2bf(float f){
  union { float f; unsigned u; } v; v.f = f;
  unsigned r = v.u + 0x7fffu + ((v.u >> 16) & 1u);
  return (short)(r >> 16);
}
__device__ __forceinline__ float ex2(float x){
  float y; asm("v_exp_f32 %0, %1" : "=v"(y) : "v"(x)); return y;
}
__device__ __forceinline__ unsigned cvtpk(float lo, float hi){
  unsigned u; asm("v_cvt_pk_bf16_f32 %0, %1, %2" : "=v"(u) : "v"(lo), "v"(hi)); return u;
}
__device__ __forceinline__ void pl32swap(unsigned &x, unsigned &y){
  asm("v_permlane32_swap_b32 %0, %1" : "+v"(x), "+v"(y));
}

// ---- K1a: GN stats -> per-quarter partial slots (no atomics, no memset);
//      blocks 256..1023: weight cvt (concurrent) ----
__global__ __launch_bounds__(256) void k_stats(const float* __restrict__ x,
                                               const float* __restrict__ pw,
                                               const float* __restrict__ ow,
                                               float* __restrict__ sbuf,
                                               short* __restrict__ pwb,
                                               short* __restrict__ owb){
  int blk = blockIdx.x;
  if (blk < 256){
    int bg = blk >> 2, qt = blk & 3;
    const float* base = x + (size_t)bg*(CPG*NS) + (size_t)qt*(CPG*NS/4);
    const f32x4* b4 = (const f32x4*)base;
    float s = 0.f, ss = 0.f;
    #pragma unroll
    for (int it = 0; it < 8; ++it){
      f32x4 v = b4[it*256 + threadIdx.x];
      s  += (v[0]+v[1])+(v[2]+v[3]);
      ss += (v[0]*v[0]+v[1]*v[1])+(v[2]*v[2]+v[3]*v[3]);
    }
    for (int o = 32; o > 0; o >>= 1){ s += __shfl_down(s,o); ss += __shfl_down(ss,o); }
    __shared__ float red[8];
    int w = threadIdx.x >> 6;
    if ((threadIdx.x & 63) == 0){ red[w] = s; red[4+w] = ss; }
    __syncthreads();
    if (threadIdx.x == 0){
      sbuf[blk]       = red[0]+red[1]+red[2]+red[3];
      sbuf[256 + blk] = red[4]+red[5]+red[6]+red[7];
    }
  } else {
    int i = (blk - 256)*256 + threadIdx.x;
    if (i < NQKV*NC) pwb[i] = f2bf(pw[i]);
    if (i < NC*NC)   owb[i] = f2bf(ow[i]);
  }
}

// ---- K1b: GN apply + transpose-write h (256 blocks); sums 4 stat partials ----
__global__ __launch_bounds__(256) void k_apply(const float* __restrict__ x,
                                               const float* __restrict__ sbuf,
                                               const float* __restrict__ gw,
                                               const float* __restrict__ gb,
                                               short* __restrict__ h){
  int blk = blockIdx.x;
  int tid = threadIdx.x;
  int bg = blk >> 2, qt = blk & 3;
  int b = bg >> 5, g = bg & 31;
  const float* base = x + (size_t)bg*(CPG*NS);
  const float inv = 1.f/(float)(CPG*NS);
  float S  = sbuf[bg*4+0] + sbuf[bg*4+1] + sbuf[bg*4+2] + sbuf[bg*4+3];
  float SS = sbuf[256+bg*4+0] + sbuf[256+bg*4+1] + sbuf[256+bg*4+2] + sbuf[256+bg*4+3];
  float mu = S*inv;
  float rs = rsqrtf(SS*inv - mu*mu + 1e-5f);
  float wv[8], bv[8];
  #pragma unroll
  for (int c = 0; c < 8; ++c){
    wv[c] = gw[g*8 + c] * rs;
    bv[c] = gb[g*8 + c] - mu * wv[c];
  }
  short* hb = h + (size_t)b*NS*NC + g*8;
  int s0 = qt << 10;
  #pragma unroll
  for (int it = 0; it < 4; ++it){
    int i = s0 + it*256 + tid;
    unsigned u[4];
    #pragma unroll
    for (int c2 = 0; c2 < 4; ++c2){
      float v0 = base[(size_t)(2*c2  )*NS + i]*wv[2*c2  ] + bv[2*c2  ];
      float v1 = base[(size_t)(2*c2+1)*NS + i]*wv[2*c2+1] + bv[2*c2+1];
      u[c2] = cvtpk(v0, v1);
    }
    *(uint4v*)&hb[(size_t)i*NC] = (uint4v){u[0],u[1],u[2],u[3]};
  }
}

// ---- K4: QKV GEMM, BM=64 BK=64 -> 768 blocks; scatter epilogue; q gets QS folded ----
__global__ __launch_bounds__(256) void k_qkv(const short* __restrict__ h,
                                             const short* __restrict__ wb,
                                             const float* __restrict__ pb,
                                             short* __restrict__ qo,
                                             short* __restrict__ ko,
                                             short* __restrict__ vto){
  __shared__ short As[64][72];
  __shared__ short Bs[128][72];
  int m0 = blockIdx.x << 6;
  int n0 = blockIdx.y << 7;
  int tid = threadIdx.x;
  int lane = tid & 63, wid = tid >> 6;
  int wm = (wid >> 1) << 5, wn = (wid & 1) << 6;
  int l15 = lane & 15, lg = lane >> 4;
  const f32x4 fz = {0.f,0.f,0.f,0.f};
  f32x4 acc[2][4];
  for (int i=0;i<2;i++) for(int j=0;j<4;j++) acc[i][j] = fz;
  for (int k0 = 0; k0 < NC; k0 += 64){
    __syncthreads();
    for (int it = 0; it < 2; ++it){
      int c = it*256 + tid;
      int r = c >> 3, ch = (c & 7) << 3;
      *(short8*)&As[r][ch] = *(const short8*)&h[((size_t)(m0 + r))*NC + k0 + ch];
    }
    for (int it = 0; it < 4; ++it){
      int c = it*256 + tid;
      int r = c >> 3, ch = (c & 7) << 3;
      *(short8*)&Bs[r][ch] = *(const short8*)&wb[((size_t)(n0 + r))*NC + k0 + ch];
    }
    __syncthreads();
    #pragma unroll
    for (int kk = 0; kk < 2; ++kk){
      short8 a[2], b[4];
      for (int mf=0; mf<2; ++mf) a[mf] = *(const short8*)&As[wm + mf*16 + l15][kk*32 + lg*8];
      for (int nf=0; nf<4; ++nf) b[nf] = *(const short8*)&Bs[wn + nf*16 + l15][kk*32 + lg*8];
      for (int mf=0; mf<2; ++mf)
        for (int nf=0; nf<4; ++nf)
          acc[mf][nf] = __builtin_amdgcn_mfma_f32_16x16x32_bf16(a[mf], b[nf], acc[mf][nf], 0,0,0);
    }
  }
  for (int mf=0; mf<2; ++mf)
    for (int nf=0; nf<4; ++nf)
      for (int r=0; r<4; ++r){
        int m = m0 + wm + mf*16 + lg*4 + r;
        int o = n0 + wn + nf*16 + l15;
        float val = acc[mf][nf][r] + pb[o];
        int b_ = m >> 12, s = m & 4095;
        int hh = o / 192, rem = o - hh*192;
        int t = rem >> 6, d = rem & 63;
        size_t bh = (size_t)(b_*NH + hh);
        if (t == 0)      qo [(bh*NS + s)*DK + d] = f2bf(val * QS);
        else if (t == 1) ko [(bh*NS + s)*DK + d] = f2bf(val);
        else             vto[(bh*DK + d)*NS + s] = f2bf(val);
      }
}

// ---- K5: flash attention (R16 structure + packed-f32 softmax):
//          256 blocks x 16 waves, dbuf LDS (1 barrier/tile), defer-rescale,
//          XCD swizzle; max/sub/sum via f32x2 -> v_pk_*_f32 (fewer issue slots) ----
struct SMK { short kv[NKG][2][2][64][72]; };   // 147456 B
struct SMC {
  float gOB[3][4][64][33];
  float ml[3][4][2][32];
  float fOB[4][64][33];
};

__global__ __launch_bounds__(1024, 4) void k_attn(const short* __restrict__ q,
                                                  const short* __restrict__ k,
                                                  const short* __restrict__ vt,
                                                  short* __restrict__ ao){
  extern __shared__ char smem[];
  SMK* sk = (SMK*)smem;
  SMC* sc = (SMC*)smem;

  int blk = blockIdx.x;
  int bh = blk & 7;                  // XCD-locality: one bh's 1MB K/V per XCD L2
  int q0 = (blk >> 3) << 7;
  const short* Qb = q  + (size_t)bh*NS*DK;
  const short* Kb = k  + (size_t)bh*NS*DK;
  const short* Vb = vt + (size_t)bh*DK*NS;
  int tid = threadIdx.x, lane = tid & 63, wid = tid >> 6;
  int l31 = lane & 31, hi = lane >> 5;
  int g = wid >> 2, wq = wid & 3;
  int gtid = tid & 255;
  int kvbase = g << 10;

  short8 bq[4];
  {
    const short* qrow = Qb + (size_t)(q0 + wq*32 + l31)*DK + hi*8;
    #pragma unroll
    for (int s2 = 0; s2 < 4; ++s2) bq[s2] = *(const short8*)(qrow + s2*16);
  }

  f32x16 ot0, ot1;
  #pragma unroll
  for (int i = 0; i < 16; ++i){ ot0[i] = 0.f; ot1[i] = 0.f; }
  float mrun = -1e30f, lrun = 0.f;

  short8 kpre[2], vpre[2];
  #pragma unroll
  for (int it = 0; it < 2; ++it){
    int c = it*256 + gtid, r = c >> 3, col = (c & 7) << 3;
    kpre[it] = *(const short8*)&Kb[(size_t)(kvbase + r)*DK + col];
    vpre[it] = *(const short8*)&Vb[(size_t)r*NS + kvbase + col];
  }
  #pragma unroll
  for (int it = 0; it < 2; ++it){
    int c = it*256 + gtid, r = c >> 3, col = (c & 7) << 3;
    *(short8*)&sk->kv[g][0][0][r][col] = kpre[it];
    *(short8*)&sk->kv[g][0][1][r][col] = vpre[it];
  }
  #pragma unroll
  for (int it = 0; it < 2; ++it){
    int c = it*256 + gtid, r = c >> 3, col = (c & 7) << 3;
    kpre[it] = *(const short8*)&Kb[(size_t)(kvbase + 64 + r)*DK + col];
    vpre[it] = *(const short8*)&Vb[(size_t)r*NS + kvbase + 64 + col];
  }

  for (int t = 0; t < TPG; ++t){
    __syncthreads();
    const short (*Kl)[72] = sk->kv[g][t & 1][0];
    const short (*Vl)[72] = sk->kv[g][t & 1][1];
    f32x16 st0, st1;
    #pragma unroll
    for (int i = 0; i < 16; ++i){ st0[i] = 0.f; st1[i] = 0.f; }
    const short* Kr0 = &Kl[l31][hi*8];
    const short* Kr1 = &Kl[32 + l31][hi*8];
    #pragma unroll
    for (int s2 = 0; s2 < 4; ++s2){
      short8 ka0 = *(const short8*)(Kr0 + s2*16);
      short8 ka1 = *(const short8*)(Kr1 + s2*16);
      st0 = __builtin_amdgcn_mfma_f32_32x32x16_bf16(ka0, bq[s2], st0, 0,0,0);
      st1 = __builtin_amdgcn_mfma_f32_32x32x16_bf16(ka1, bq[s2], st1, 0,0,0);
    }
    if (t + 1 < TPG){
      int nb = (t + 1) & 1;
      #pragma unroll
      for (int it = 0; it < 2; ++it){
        int c = it*256 + gtid, r = c >> 3, col = (c & 7) << 3;
        *(short8*)&sk->kv[g][nb][0][r][col] = kpre[it];
        *(short8*)&sk->kv[g][nb][1][r][col] = vpre[it];
      }
    }
    if (t + 2 < TPG){
      int kv0 = kvbase + (t + 2)*64;
      #pragma unroll
      for (int it = 0; it < 2; ++it){
        int c = it*256 + gtid, r = c >> 3, col = (c & 7) << 3;
        kpre[it] = *(const short8*)&Kb[(size_t)(kv0 + r)*DK + col];
        vpre[it] = *(const short8*)&Vb[(size_t)r*NS + kv0 + col];
      }
    }
    // ---- packed softmax: f32x2 ops lower to v_pk_max_f32 / v_pk_add_f32 ----
    f32x2 m2 = { -1e30f, -1e30f };
    #pragma unroll
    for (int i = 0; i < 8; ++i){
      f32x2 a0 = { st0[2*i], st0[2*i+1] };
      f32x2 a1 = { st1[2*i], st1[2*i+1] };
      m2 = __builtin_elementwise_max(m2, __builtin_elementwise_max(a0, a1));
    }
    float mx = fmaxf(m2[0], m2[1]);
    mx = fmaxf(mx, __shfl_xor(mx, 32));
    if (!__all(mx - mrun <= 8.f)){   // defer-rescale: P bounded by 2^8
      float mnew = fmaxf(mrun, mx);
      float corr = ex2(mrun - mnew);
      lrun *= corr;
      #pragma unroll
      for (int i = 0; i < 16; ++i){ ot0[i] *= corr; ot1[i] *= corr; }
      mrun = mnew;
    }
    float p0[16], p1[16];
    f32x2 s2v = { 0.f, 0.f };
    f32x2 nm = { -mrun, -mrun };
    #pragma unroll
    for (int i = 0; i < 8; ++i){
      f32x2 a0 = (f32x2){ st0[2*i], st0[2*i+1] } + nm;   // v_pk_add_f32
      f32x2 a1 = (f32x2){ st1[2*i], st1[2*i+1] } + nm;
      p0[2*i] = ex2(a0[0]); p0[2*i+1] = ex2(a0[1]);
      p1[2*i] = ex2(a1[0]); p1[2*i+1] = ex2(a1[1]);
      f32x2 q0v = { p0[2*i], p0[2*i+1] };
      f32x2 q1v = { p1[2*i], p1[2*i+1] };
      s2v += q0v + q1v;                                   // v_pk_add_f32
    }
    float ps = s2v[0] + s2v[1];
    ps += __shfl_xor(ps, 32);
    lrun += ps;
    unsigned pk0[8], pk1[8];
    #pragma unroll
    for (int a = 0; a < 4; ++a){
      pk0[a]     = cvtpk(p0[4*a+0], p0[4*a+1]);
      pk1[a]     = cvtpk(p0[4*a+2], p0[4*a+3]);
      pk0[4 + a] = cvtpk(p1[4*a+0], p1[4*a+1]);
      pk1[4 + a] = cvtpk(p1[4*a+2], p1[4*a+3]);
    }
    const short* Vr0 = &Vl[l31][hi*8];
    const short* Vr1 = &Vl[32 + l31][hi*8];
    #pragma unroll
    for (int i2 = 0; i2 < 4; ++i2){
      unsigned w0 = pk0[2*i2], w2 = pk0[2*i2+1]; pl32swap(w0, w2);
      unsigned w1 = pk1[2*i2], w3 = pk1[2*i2+1]; pl32swap(w1, w3);
      U8 cv; cv.u = (uint4v){w0, w1, w2, w3};
      short8 av0 = *(const short8*)(Vr0 + i2*16);
      short8 av1 = *(const short8*)(Vr1 + i2*16);
      ot0 = __builtin_amdgcn_mfma_f32_32x32x16_bf16(av0, cv.s, ot0, 0,0,0);
      ot1 = __builtin_amdgcn_mfma_f32_32x32x16_bf16(av1, cv.s, ot1, 0,0,0);
    }
  }

  __syncthreads();
  if (g > 0){
    #pragma unroll
    for (int r2 = 0; r2 < 16; ++r2){
      int dl = (r2 & 3) + 8*(r2 >> 2) + 4*hi;
      sc->gOB[g-1][wq][dl][l31]      = ot0[r2];
      sc->gOB[g-1][wq][32 + dl][l31] = ot1[r2];
    }
    if (hi == 0){ sc->ml[g-1][wq][0][l31] = mrun; sc->ml[g-1][wq][1][l31] = lrun; }
  }
  __syncthreads();
  if (g == 0){
    float m1 = sc->ml[0][wq][0][l31], l1 = sc->ml[0][wq][1][l31];
    float m2_ = sc->ml[1][wq][0][l31], l2 = sc->ml[1][wq][1][l31];
    float m3 = sc->ml[2][wq][0][l31], l3 = sc->ml[2][wq][1][l31];
    float M  = fmaxf(fmaxf(mrun, m1), fmaxf(m2_, m3));
    float w0 = ex2(mrun - M), w1 = ex2(m1 - M), w2 = ex2(m2_ - M), w3 = ex2(m3 - M);
    float inv = 1.f/(lrun*w0 + l1*w1 + l2*w2 + l3*w3);
    w0 *= inv; w1 *= inv; w2 *= inv; w3 *= inv;
    #pragma unroll
    for (int r2 = 0; r2 < 16; ++r2){
      int dl = (r2 & 3) + 8*(r2 >> 2) + 4*hi;
      sc->fOB[wq][dl][l31] = ot0[r2]*w0 + sc->gOB[0][wq][dl][l31]*w1
                           + sc->gOB[1][wq][dl][l31]*w2 + sc->gOB[2][wq][dl][l31]*w3;
      sc->fOB[wq][32+dl][l31] = ot1[r2]*w0 + sc->gOB[0][wq][32+dl][l31]*w1
                              + sc->gOB[1][wq][32+dl][l31]*w2 + sc->gOB[2][wq][32+dl][l31]*w3;
    }
  }
  __syncthreads();
  {
    int ql = tid >> 3, dc = (tid & 7) << 3;
    int b_ = bh >> 2, hh = bh & 3;
    float v2[8];
    #pragma unroll
    for (int i = 0; i < 8; ++i) v2[i] = sc->fOB[ql >> 5][dc + i][ql & 31];
    uint4v wa = { cvtpk(v2[0],v2[1]), cvtpk(v2[2],v2[3]),
                  cvtpk(v2[4],v2[5]), cvtpk(v2[6],v2[7]) };
    size_t base = ((size_t)b_*NS + q0 + ql)*NC + hh*DK + dc;
    *(uint4v*)&ao[base] = wa;
  }
}

// ---- K6: out GEMM + bias + residual, BM=64 BN=64 -> 512 blocks ----
__global__ __launch_bounds__(256) void k_out(const short* __restrict__ aoin,
                                             const short* __restrict__ wb,
                                             const float* __restrict__ ob,
                                             const float* __restrict__ x,
                                             float* __restrict__ out){
  __shared__ short As[64][40];
  __shared__ short Bs[64][40];
  int m0 = blockIdx.x << 6;
  int n0 = blockIdx.y << 6;
  int tid = threadIdx.x;
  int lane = tid & 63, wid = tid >> 6;
  int wm = (wid >> 1) << 5, wn = (wid & 1) << 5;
  int l15 = lane & 15, lg = lane >> 4;
  const f32x4 fz = {0.f,0.f,0.f,0.f};
  f32x4 acc[2][2];
  for (int i=0;i<2;i++) for(int j=0;j<2;j++) acc[i][j] = fz;
  for (int k0 = 0; k0 < NC; k0 += 32){
    __syncthreads();
    {
      int c = tid;
      int r = c >> 2, kk8 = (c & 3) << 3;
      *(short8*)&As[r][kk8] = *(const short8*)&aoin[((size_t)(m0 + r))*NC + k0 + kk8];
      *(short8*)&Bs[r][kk8] = *(const short8*)&wb  [((size_t)(n0 + r))*NC + k0 + kk8];
    }
    __syncthreads();
    short8 a[2], b[2];
    for (int mf=0; mf<2; ++mf) a[mf] = *(const short8*)&As[wm + mf*16 + l15][lg*8];
    for (int nf=0; nf<2; ++nf) b[nf] = *(const short8*)&Bs[wn + nf*16 + l15][lg*8];
    for (int mf=0; mf<2; ++mf)
      for (int nf=0; nf<2; ++nf)
        acc[mf][nf] = __builtin_amdgcn_mfma_f32_16x16x32_bf16(a[mf], b[nf], acc[mf][nf], 0,0,0);
  }
  for (int mf=0; mf<2; ++mf)
    for (int nf=0; nf<2; ++nf)
      for (int r=0; r<4; ++r){
        int m = m0 + wm + mf*16 + lg*4 + r;
        int o = n0 + wn + nf*16 + l15;
        int b_ = m >> 12, s = m & 4095;
        size_t idx = ((size_t)b_*NC + o)*NS + s;
        out[idx] = acc[mf][nf][r] + ob[o] + x[idx];
      }
}

extern "C" void kernel_launch(void* const* d_in, const int* in_sizes, int n_in,
                              void* d_out, int out_size, void* d_ws, size_t ws_size,
                              hipStream_t stream){
  const float* x   = (const float*)d_in[0];
  const float* gnw = (const float*)d_in[1];
  const float* gnb = (const float*)d_in[2];
  const float* pw  = (const float*)d_in[3];
  const float* pb  = (const float*)d_in[4];
  const float* ow  = (const float*)d_in[5];
  const float* ob  = (const float*)d_in[6];
  float* out = (float*)d_out;

  char* ws = (char*)d_ws;
  float* sbuf = (float*)ws;                          // [512] f32: S[256], SS[256] partials
  short* wqkv = (short*)(ws + 2048);
  short* wout = wqkv + NQKV*NC;
  short* h    = wout + NC*NC;
  short* qb   = h   + (size_t)NB*NS*NC;
  short* kb   = qb  + (size_t)NB*NH*NS*DK;
  short* vtb  = kb  + (size_t)NB*NH*NS*DK;
  short* ao   = vtb + (size_t)NB*NH*NS*DK;

  k_stats<<<1024, 256, 0, stream>>>(x, pw, ow, sbuf, wqkv, wout);
  k_apply<<<256, 256, 0, stream>>>(x, sbuf, gnw, gnb, h);
  k_qkv<<<dim3(128, 6), 256, 0, stream>>>(h, wqkv, pb, qb, kb, vtb);
  k_attn<<<256, 1024, sizeof(SMK), stream>>>(qb, kb, vtb, ao);
  k_out<<<dim3(128, 4), 256, 0, stream>>>(ao, wout, ob, x, out);
}

// Round 20
// 86.012 us; speedup vs baseline: 1.8702x; 1.0041x over previous
//
#include <hip/hip_runtime.h>
#include <math.h>

#define NB 2
#define NC 256
#define NS 4096
#define NG 32
#define CPG 8
#define NH 4
#define DK 64
#define NQKV 768
#define NKG 4
#define TPG 16
#define QS 0.18033688011112042f   /* 0.125 * log2(e) */

typedef __attribute__((ext_vector_type(8))) short short8;
typedef __attribute__((ext_vector_type(4))) float f32x4;
typedef __attribute__((ext_vector_type(16))) float f32x16;
typedef __attribute__((ext_vector_type(4))) unsigned uint4v;

union U8 { uint4v u; short8 s; };

__device__ __forceinline__ short f2bf(float f){
  union { float f; unsigned u; } v; v.f = f;
  unsigned r = v.u + 0x7fffu + ((v.u >> 16) & 1u);
  return (short)(r >> 16);
}
__device__ __forceinline__ float ex2(float x){
  float y; asm("v_exp_f32 %0, %1" : "=v"(y) : "v"(x)); return y;
}
__device__ __forceinline__ unsigned cvtpk(float lo, float hi){
  unsigned u; asm("v_cvt_pk_bf16_f32 %0, %1, %2" : "=v"(u) : "v"(lo), "v"(hi)); return u;
}
__device__ __forceinline__ void pl32swap(unsigned &x, unsigned &y){
  asm("v_permlane32_swap_b32 %0, %1" : "+v"(x), "+v"(y));
}

// ---- K1a: GN stats -> per-quarter partial slots (no atomics, no memset);
//      blocks 256..1023: weight cvt (concurrent) ----
__global__ __launch_bounds__(256) void k_stats(const float* __restrict__ x,
                                               const float* __restrict__ pw,
                                               const float* __restrict__ ow,
                                               float* __restrict__ sbuf,
                                               short* __restrict__ pwb,
                                               short* __restrict__ owb){
  int blk = blockIdx.x;
  if (blk < 256){
    int bg = blk >> 2, qt = blk & 3;
    const float* base = x + (size_t)bg*(CPG*NS) + (size_t)qt*(CPG*NS/4);
    const f32x4* b4 = (const f32x4*)base;
    float s = 0.f, ss = 0.f;
    #pragma unroll
    for (int it = 0; it < 8; ++it){
      f32x4 v = b4[it*256 + threadIdx.x];
      s  += (v[0]+v[1])+(v[2]+v[3]);
      ss += (v[0]*v[0]+v[1]*v[1])+(v[2]*v[2]+v[3]*v[3]);
    }
    for (int o = 32; o > 0; o >>= 1){ s += __shfl_down(s,o); ss += __shfl_down(ss,o); }
    __shared__ float red[8];
    int w = threadIdx.x >> 6;
    if ((threadIdx.x & 63) == 0){ red[w] = s; red[4+w] = ss; }
    __syncthreads();
    if (threadIdx.x == 0){
      sbuf[blk]       = red[0]+red[1]+red[2]+red[3];
      sbuf[256 + blk] = red[4]+red[5]+red[6]+red[7];
    }
  } else {
    int i = (blk - 256)*256 + threadIdx.x;
    if (i < NQKV*NC) pwb[i] = f2bf(pw[i]);
    if (i < NC*NC)   owb[i] = f2bf(ow[i]);
  }
}

// ---- K1b: GN apply + transpose-write h (256 blocks); sums 4 stat partials ----
__global__ __launch_bounds__(256) void k_apply(const float* __restrict__ x,
                                               const float* __restrict__ sbuf,
                                               const float* __restrict__ gw,
                                               const float* __restrict__ gb,
                                               short* __restrict__ h){
  int blk = blockIdx.x;
  int tid = threadIdx.x;
  int bg = blk >> 2, qt = blk & 3;
  int b = bg >> 5, g = bg & 31;
  const float* base = x + (size_t)bg*(CPG*NS);
  const float inv = 1.f/(float)(CPG*NS);
  float S  = sbuf[bg*4+0] + sbuf[bg*4+1] + sbuf[bg*4+2] + sbuf[bg*4+3];
  float SS = sbuf[256+bg*4+0] + sbuf[256+bg*4+1] + sbuf[256+bg*4+2] + sbuf[256+bg*4+3];
  float mu = S*inv;
  float rs = rsqrtf(SS*inv - mu*mu + 1e-5f);
  float wv[8], bv[8];
  #pragma unroll
  for (int c = 0; c < 8; ++c){
    wv[c] = gw[g*8 + c] * rs;
    bv[c] = gb[g*8 + c] - mu * wv[c];
  }
  short* hb = h + (size_t)b*NS*NC + g*8;
  int s0 = qt << 10;
  #pragma unroll
  for (int it = 0; it < 4; ++it){
    int i = s0 + it*256 + tid;
    unsigned u[4];
    #pragma unroll
    for (int c2 = 0; c2 < 4; ++c2){
      float v0 = base[(size_t)(2*c2  )*NS + i]*wv[2*c2  ] + bv[2*c2  ];
      float v1 = base[(size_t)(2*c2+1)*NS + i]*wv[2*c2+1] + bv[2*c2+1];
      u[c2] = cvtpk(v0, v1);
    }
    *(uint4v*)&hb[(size_t)i*NC] = (uint4v){u[0],u[1],u[2],u[3]};
  }
}

// ---- K4: QKV GEMM, BM=64 BK=64 -> 768 blocks; scatter epilogue; q gets QS folded ----
__global__ __launch_bounds__(256) void k_qkv(const short* __restrict__ h,
                                             const short* __restrict__ wb,
                                             const float* __restrict__ pb,
                                             short* __restrict__ qo,
                                             short* __restrict__ ko,
                                             short* __restrict__ vto){
  __shared__ short As[64][72];
  __shared__ short Bs[128][72];
  int m0 = blockIdx.x << 6;
  int n0 = blockIdx.y << 7;
  int tid = threadIdx.x;
  int lane = tid & 63, wid = tid >> 6;
  int wm = (wid >> 1) << 5, wn = (wid & 1) << 6;
  int l15 = lane & 15, lg = lane >> 4;
  const f32x4 fz = {0.f,0.f,0.f,0.f};
  f32x4 acc[2][4];
  for (int i=0;i<2;i++) for(int j=0;j<4;j++) acc[i][j] = fz;
  for (int k0 = 0; k0 < NC; k0 += 64){
    __syncthreads();
    for (int it = 0; it < 2; ++it){
      int c = it*256 + tid;
      int r = c >> 3, ch = (c & 7) << 3;
      *(short8*)&As[r][ch] = *(const short8*)&h[((size_t)(m0 + r))*NC + k0 + ch];
    }
    for (int it = 0; it < 4; ++it){
      int c = it*256 + tid;
      int r = c >> 3, ch = (c & 7) << 3;
      *(short8*)&Bs[r][ch] = *(const short8*)&wb[((size_t)(n0 + r))*NC + k0 + ch];
    }
    __syncthreads();
    #pragma unroll
    for (int kk = 0; kk < 2; ++kk){
      short8 a[2], b[4];
      for (int mf=0; mf<2; ++mf) a[mf] = *(const short8*)&As[wm + mf*16 + l15][kk*32 + lg*8];
      for (int nf=0; nf<4; ++nf) b[nf] = *(const short8*)&Bs[wn + nf*16 + l15][kk*32 + lg*8];
      for (int mf=0; mf<2; ++mf)
        for (int nf=0; nf<4; ++nf)
          acc[mf][nf] = __builtin_amdgcn_mfma_f32_16x16x32_bf16(a[mf], b[nf], acc[mf][nf], 0,0,0);
    }
  }
  for (int mf=0; mf<2; ++mf)
    for (int nf=0; nf<4; ++nf)
      for (int r=0; r<4; ++r){
        int m = m0 + wm + mf*16 + lg*4 + r;
        int o = n0 + wn + nf*16 + l15;
        float val = acc[mf][nf][r] + pb[o];
        int b_ = m >> 12, s = m & 4095;
        int hh = o / 192, rem = o - hh*192;
        int t = rem >> 6, d = rem & 63;
        size_t bh = (size_t)(b_*NH + hh);
        if (t == 0)      qo [(bh*NS + s)*DK + d] = f2bf(val * QS);
        else if (t == 1) ko [(bh*NS + s)*DK + d] = f2bf(val);
        else             vto[(bh*DK + d)*NS + s] = f2bf(val);
      }
}

// ---- K5: flash attention (R16-proven body, serial softmax): 256 blocks x 16 waves,
//          dbuf LDS (1 barrier/tile), defer-rescale, XCD swizzle ----
struct SMK { short kv[NKG][2][2][64][72]; };   // 147456 B
struct SMC {
  float gOB[3][4][64][33];
  float ml[3][4][2][32];
  float fOB[4][64][33];
};

__global__ __launch_bounds__(1024, 4) void k_attn(const short* __restrict__ q,
                                                  const short* __restrict__ k,
                                                  const short* __restrict__ vt,
                                                  short* __restrict__ ao){
  extern __shared__ char smem[];
  SMK* sk = (SMK*)smem;
  SMC* sc = (SMC*)smem;

  int blk = blockIdx.x;
  int bh = blk & 7;                  // XCD-locality: one bh's 1MB K/V per XCD L2
  int q0 = (blk >> 3) << 7;
  const short* Qb = q  + (size_t)bh*NS*DK;
  const short* Kb = k  + (size_t)bh*NS*DK;
  const short* Vb = vt + (size_t)bh*DK*NS;
  int tid = threadIdx.x, lane = tid & 63, wid = tid >> 6;
  int l31 = lane & 31, hi = lane >> 5;
  int g = wid >> 2, wq = wid & 3;
  int gtid = tid & 255;
  int kvbase = g << 10;

  short8 bq[4];
  {
    const short* qrow = Qb + (size_t)(q0 + wq*32 + l31)*DK + hi*8;
    #pragma unroll
    for (int s2 = 0; s2 < 4; ++s2) bq[s2] = *(const short8*)(qrow + s2*16);
  }

  f32x16 ot0, ot1;
  #pragma unroll
  for (int i = 0; i < 16; ++i){ ot0[i] = 0.f; ot1[i] = 0.f; }
  float mrun = -1e30f, lrun = 0.f;

  short8 kpre[2], vpre[2];
  #pragma unroll
  for (int it = 0; it < 2; ++it){
    int c = it*256 + gtid, r = c >> 3, col = (c & 7) << 3;
    kpre[it] = *(const short8*)&Kb[(size_t)(kvbase + r)*DK + col];
    vpre[it] = *(const short8*)&Vb[(size_t)r*NS + kvbase + col];
  }
  #pragma unroll
  for (int it = 0; it < 2; ++it){
    int c = it*256 + gtid, r = c >> 3, col = (c & 7) << 3;
    *(short8*)&sk->kv[g][0][0][r][col] = kpre[it];
    *(short8*)&sk->kv[g][0][1][r][col] = vpre[it];
  }
  #pragma unroll
  for (int it = 0; it < 2; ++it){
    int c = it*256 + gtid, r = c >> 3, col = (c & 7) << 3;
    kpre[it] = *(const short8*)&Kb[(size_t)(kvbase + 64 + r)*DK + col];
    vpre[it] = *(const short8*)&Vb[(size_t)r*NS + kvbase + 64 + col];
  }

  for (int t = 0; t < TPG; ++t){
    __syncthreads();
    const short (*Kl)[72] = sk->kv[g][t & 1][0];
    const short (*Vl)[72] = sk->kv[g][t & 1][1];
    f32x16 st0, st1;
    #pragma unroll
    for (int i = 0; i < 16; ++i){ st0[i] = 0.f; st1[i] = 0.f; }
    const short* Kr0 = &Kl[l31][hi*8];
    const short* Kr1 = &Kl[32 + l31][hi*8];
    #pragma unroll
    for (int s2 = 0; s2 < 4; ++s2){
      short8 ka0 = *(const short8*)(Kr0 + s2*16);
      short8 ka1 = *(const short8*)(Kr1 + s2*16);
      st0 = __builtin_amdgcn_mfma_f32_32x32x16_bf16(ka0, bq[s2], st0, 0,0,0);
      st1 = __builtin_amdgcn_mfma_f32_32x32x16_bf16(ka1, bq[s2], st1, 0,0,0);
    }
    if (t + 1 < TPG){
      int nb = (t + 1) & 1;
      #pragma unroll
      for (int it = 0; it < 2; ++it){
        int c = it*256 + gtid, r = c >> 3, col = (c & 7) << 3;
        *(short8*)&sk->kv[g][nb][0][r][col] = kpre[it];
        *(short8*)&sk->kv[g][nb][1][r][col] = vpre[it];
      }
    }
    if (t + 2 < TPG){
      int kv0 = kvbase + (t + 2)*64;
      #pragma unroll
      for (int it = 0; it < 2; ++it){
        int c = it*256 + gtid, r = c >> 3, col = (c & 7) << 3;
        kpre[it] = *(const short8*)&Kb[(size_t)(kv0 + r)*DK + col];
        vpre[it] = *(const short8*)&Vb[(size_t)r*NS + kv0 + col];
      }
    }
    float mx = -1e30f;
    #pragma unroll
    for (int i = 0; i < 16; ++i) mx = fmaxf(mx, fmaxf(st0[i], st1[i]));
    mx = fmaxf(mx, __shfl_xor(mx, 32));
    if (!__all(mx - mrun <= 8.f)){   // defer-rescale: P bounded by 2^8
      float mnew = fmaxf(mrun, mx);
      float corr = ex2(mrun - mnew);
      lrun *= corr;
      #pragma unroll
      for (int i = 0; i < 16; ++i){ ot0[i] *= corr; ot1[i] *= corr; }
      mrun = mnew;
    }
    float p0[16], p1[16]; float ps = 0.f;
    #pragma unroll
    for (int i = 0; i < 16; ++i){
      p0[i] = ex2(st0[i] - mrun); p1[i] = ex2(st1[i] - mrun);
      ps += p0[i] + p1[i];
    }
    ps += __shfl_xor(ps, 32);
    lrun += ps;
    unsigned pk0[8], pk1[8];
    #pragma unroll
    for (int a = 0; a < 4; ++a){
      pk0[a]     = cvtpk(p0[4*a+0], p0[4*a+1]);
      pk1[a]     = cvtpk(p0[4*a+2], p0[4*a+3]);
      pk0[4 + a] = cvtpk(p1[4*a+0], p1[4*a+1]);
      pk1[4 + a] = cvtpk(p1[4*a+2], p1[4*a+3]);
    }
    const short* Vr0 = &Vl[l31][hi*8];
    const short* Vr1 = &Vl[32 + l31][hi*8];
    #pragma unroll
    for (int i2 = 0; i2 < 4; ++i2){
      unsigned w0 = pk0[2*i2], w2 = pk0[2*i2+1]; pl32swap(w0, w2);
      unsigned w1 = pk1[2*i2], w3 = pk1[2*i2+1]; pl32swap(w1, w3);
      U8 cv; cv.u = (uint4v){w0, w1, w2, w3};
      short8 av0 = *(const short8*)(Vr0 + i2*16);
      short8 av1 = *(const short8*)(Vr1 + i2*16);
      ot0 = __builtin_amdgcn_mfma_f32_32x32x16_bf16(av0, cv.s, ot0, 0,0,0);
      ot1 = __builtin_amdgcn_mfma_f32_32x32x16_bf16(av1, cv.s, ot1, 0,0,0);
    }
  }

  __syncthreads();
  if (g > 0){
    #pragma unroll
    for (int r2 = 0; r2 < 16; ++r2){
      int dl = (r2 & 3) + 8*(r2 >> 2) + 4*hi;
      sc->gOB[g-1][wq][dl][l31]      = ot0[r2];
      sc->gOB[g-1][wq][32 + dl][l31] = ot1[r2];
    }
    if (hi == 0){ sc->ml[g-1][wq][0][l31] = mrun; sc->ml[g-1][wq][1][l31] = lrun; }
  }
  __syncthreads();
  if (g == 0){
    float m1 = sc->ml[0][wq][0][l31], l1 = sc->ml[0][wq][1][l31];
    float m2 = sc->ml[1][wq][0][l31], l2 = sc->ml[1][wq][1][l31];
    float m3 = sc->ml[2][wq][0][l31], l3 = sc->ml[2][wq][1][l31];
    float M  = fmaxf(fmaxf(mrun, m1), fmaxf(m2, m3));
    float w0 = ex2(mrun - M), w1 = ex2(m1 - M), w2 = ex2(m2 - M), w3 = ex2(m3 - M);
    float inv = 1.f/(lrun*w0 + l1*w1 + l2*w2 + l3*w3);
    w0 *= inv; w1 *= inv; w2 *= inv; w3 *= inv;
    #pragma unroll
    for (int r2 = 0; r2 < 16; ++r2){
      int dl = (r2 & 3) + 8*(r2 >> 2) + 4*hi;
      sc->fOB[wq][dl][l31] = ot0[r2]*w0 + sc->gOB[0][wq][dl][l31]*w1
                           + sc->gOB[1][wq][dl][l31]*w2 + sc->gOB[2][wq][dl][l31]*w3;
      sc->fOB[wq][32+dl][l31] = ot1[r2]*w0 + sc->gOB[0][wq][32+dl][l31]*w1
                              + sc->gOB[1][wq][32+dl][l31]*w2 + sc->gOB[2][wq][32+dl][l31]*w3;
    }
  }
  __syncthreads();
  {
    int ql = tid >> 3, dc = (tid & 7) << 3;
    int b_ = bh >> 2, hh = bh & 3;
    float v2[8];
    #pragma unroll
    for (int i = 0; i < 8; ++i) v2[i] = sc->fOB[ql >> 5][dc + i][ql & 31];
    uint4v wa = { cvtpk(v2[0],v2[1]), cvtpk(v2[2],v2[3]),
                  cvtpk(v2[4],v2[5]), cvtpk(v2[6],v2[7]) };
    size_t base = ((size_t)b_*NS + q0 + ql)*NC + hh*DK + dc;
    *(uint4v*)&ao[base] = wa;
  }
}

// ---- K6: out GEMM + bias + residual, BM=64 BN=64 -> 512 blocks ----
__global__ __launch_bounds__(256) void k_out(const short* __restrict__ aoin,
                                             const short* __restrict__ wb,
                                             const float* __restrict__ ob,
                                             const float* __restrict__ x,
                                             float* __restrict__ out){
  __shared__ short As[64][40];
  __shared__ short Bs[64][40];
  int m0 = blockIdx.x << 6;
  int n0 = blockIdx.y << 6;
  int tid = threadIdx.x;
  int lane = tid & 63, wid = tid >> 6;
  int wm = (wid >> 1) << 5, wn = (wid & 1) << 5;
  int l15 = lane & 15, lg = lane >> 4;
  const f32x4 fz = {0.f,0.f,0.f,0.f};
  f32x4 acc[2][2];
  for (int i=0;i<2;i++) for(int j=0;j<2;j++) acc[i][j] = fz;
  for (int k0 = 0; k0 < NC; k0 += 32){
    __syncthreads();
    {
      int c = tid;
      int r = c >> 2, kk8 = (c & 3) << 3;
      *(short8*)&As[r][kk8] = *(const short8*)&aoin[((size_t)(m0 + r))*NC + k0 + kk8];
      *(short8*)&Bs[r][kk8] = *(const short8*)&wb  [((size_t)(n0 + r))*NC + k0 + kk8];
    }
    __syncthreads();
    short8 a[2], b[2];
    for (int mf=0; mf<2; ++mf) a[mf] = *(const short8*)&As[wm + mf*16 + l15][lg*8];
    for (int nf=0; nf<2; ++nf) b[nf] = *(const short8*)&Bs[wn + nf*16 + l15][lg*8];
    for (int mf=0; mf<2; ++mf)
      for (int nf=0; nf<2; ++nf)
        acc[mf][nf] = __builtin_amdgcn_mfma_f32_16x16x32_bf16(a[mf], b[nf], acc[mf][nf], 0,0,0);
  }
  for (int mf=0; mf<2; ++mf)
    for (int nf=0; nf<2; ++nf)
      for (int r=0; r<4; ++r){
        int m = m0 + wm + mf*16 + lg*4 + r;
        int o = n0 + wn + nf*16 + l15;
        int b_ = m >> 12, s = m & 4095;
        size_t idx = ((size_t)b_*NC + o)*NS + s;
        out[idx] = acc[mf][nf][r] + ob[o] + x[idx];
      }
}

extern "C" void kernel_launch(void* const* d_in, const int* in_sizes, int n_in,
                              void* d_out, int out_size, void* d_ws, size_t ws_size,
                              hipStream_t stream){
  const float* x   = (const float*)d_in[0];
  const float* gnw = (const float*)d_in[1];
  const float* gnb = (const float*)d_in[2];
  const float* pw  = (const float*)d_in[3];
  const float* pb  = (const float*)d_in[4];
  const float* ow  = (const float*)d_in[5];
  const float* ob  = (const float*)d_in[6];
  float* out = (float*)d_out;

  char* ws = (char*)d_ws;
  float* sbuf = (float*)ws;                          // [512] f32: S[256], SS[256] partials
  short* wqkv = (short*)(ws + 2048);
  short* wout = wqkv + NQKV*NC;
  short* h    = wout + NC*NC;
  short* qb   = h   + (size_t)NB*NS*NC;
  short* kb   = qb  + (size_t)NB*NH*NS*DK;
  short* vtb  = kb  + (size_t)NB*NH*NS*DK;
  short* ao   = vtb + (size_t)NB*NH*NS*DK;

  k_stats<<<1024, 256, 0, stream>>>(x, pw, ow, sbuf, wqkv, wout);
  k_apply<<<256, 256, 0, stream>>>(x, sbuf, gnw, gnb, h);
  k_qkv<<<dim3(128, 6), 256, 0, stream>>>(h, wqkv, pb, qb, kb, vtb);
  k_attn<<<256, 1024, sizeof(SMK), stream>>>(qb, kb, vtb, ao);
  k_out<<<dim3(128, 4), 256, 0, stream>>>(ao, wout, ob, x, out);
}